// Round 4
// baseline (718.822 us; speedup 1.0000x reference)
//
#include <hip/hip_runtime.h>
#include <cstdint>
#include <cstddef>

static constexpr int IN_DIM = 512;
static constexpr int HID = 128;
static constexpr int OUT_DIM = 64;

typedef __attribute__((ext_vector_type(8))) short bf16x8;
typedef __attribute__((ext_vector_type(4))) float f32x4;

__device__ inline unsigned short f2bf(float x) {
    unsigned u = __float_as_uint(x);
    unsigned r = (u + 0x7FFFu + ((u >> 16) & 1u)) >> 16;   // RNE
    return (unsigned short)r;
}
__device__ inline float bf2f(unsigned short b) { return __uint_as_float(((unsigned)b) << 16); }
__device__ inline float bflo(unsigned u) { return __uint_as_float(u << 16); }
__device__ inline float bfhi(unsigned u) { return __uint_as_float(u & 0xFFFF0000u); }

// ---------------- CSR construction (counting sort by dst, rebuilt every call) ----------------

__global__ void k_hist(const int* __restrict__ dst, int E, int* __restrict__ counts) {
    int e = blockIdx.x * blockDim.x + threadIdx.x;
    if (e < E) atomicAdd(&counts[dst[e]], 1);
}

__global__ void k_scan1(const int* __restrict__ counts, int N, int* __restrict__ offs,
                        int* __restrict__ bsums) {
    __shared__ int sm[1024];
    int i = blockIdx.x * 1024 + threadIdx.x;
    int v = (i < N) ? counts[i] : 0;
    sm[threadIdx.x] = v;
    __syncthreads();
    for (int d = 1; d < 1024; d <<= 1) {
        int t = (threadIdx.x >= d) ? sm[threadIdx.x - d] : 0;
        __syncthreads();
        sm[threadIdx.x] += t;
        __syncthreads();
    }
    if (i < N) offs[i] = sm[threadIdx.x] - v;
    if (threadIdx.x == 1023) bsums[blockIdx.x] = sm[1023];
}

__global__ void k_scan2(int* __restrict__ bsums, int nb) {
    __shared__ int sm[256];
    int x = threadIdx.x;
    int v = (x < nb) ? bsums[x] : 0;
    sm[x] = v;
    __syncthreads();
    for (int d = 1; d < 256; d <<= 1) {
        int t = (x >= d) ? sm[x - d] : 0;
        __syncthreads();
        sm[x] += t;
        __syncthreads();
    }
    if (x < nb) bsums[x] = sm[x] - v;
}

__global__ void k_scan3(int* __restrict__ offs, const int* __restrict__ bsums, int N, int E,
                        int* __restrict__ cursor) {
    int i = blockIdx.x * 1024 + threadIdx.x;
    if (i < N) {
        int o = offs[i] + bsums[blockIdx.x];
        offs[i] = o;
        cursor[i] = o;
    }
    if (blockIdx.x == 0 && threadIdx.x == 0) offs[N] = E;
}

__global__ void k_dinv(const int* __restrict__ counts, int N, float* __restrict__ dinv) {
    int i = blockIdx.x * blockDim.x + threadIdx.x;
    if (i < N) dinv[i] = rsqrtf((float)(counts[i] + 1));
}

__global__ void k_fill(const int* __restrict__ src, const int* __restrict__ dst, int E,
                       int* __restrict__ cursor, int* __restrict__ ssrc) {
    int e = blockIdx.x * blockDim.x + threadIdx.x;
    if (e < E) {
        int p = atomicAdd(&cursor[dst[e]], 1);
        ssrc[p] = src[e];
    }
}

// ---------------- W split+repack into MFMA B-fragment order ----------------
// idx = ((f*KG + kg)*64 + lane)*8 + j ; col = f*16 + (lane&15), k = kg*32 + (lane>>4)*8 + j

__global__ void k_splitW(const float* __restrict__ W, int K, int M,
                         unsigned short* __restrict__ whi, unsigned short* __restrict__ wlo) {
    int idx = blockIdx.x * 256 + threadIdx.x;
    int total = K * M;
    if (idx >= total) return;
    int j = idx & 7;
    int l = (idx >> 3) & 63;
    int rest = idx >> 9;
    int KG = K >> 5;
    int kg = rest % KG;
    int f = rest / KG;
    int c = l & 15, g = l >> 4;
    int k = kg * 32 + g * 8 + j;
    int col = f * 16 + c;
    float v = W[(size_t)k * M + col];
    unsigned short h = f2bf(v);
    whi[idx] = h;
    wlo[idx] = f2bf(v - bf2f(h));
}

// ------- layer-1 GEMM: C_bf16 = dinv ⊙ (A_f32[N,K] @ W[K,M]); 3-term split, 16 rows/wave -------

template <int K, int M>
__global__ __launch_bounds__(256) void k_gemm1(const float* __restrict__ A,
                                               const unsigned short* __restrict__ whi,
                                               const unsigned short* __restrict__ wlo,
                                               const float* __restrict__ dinv,
                                               unsigned short* __restrict__ Cout, int N) {
    constexpr int NF = M / 16;
    constexpr int KG = K / 32;
    const int wave = threadIdx.x >> 6;
    const int lane = threadIdx.x & 63;
    const int c = lane & 15, g = lane >> 4;
    const int r0 = blockIdx.x * 64 + wave * 16;

    f32x4 acc[NF];
#pragma unroll
    for (int f = 0; f < NF; f++) acc[f] = (f32x4){0.f, 0.f, 0.f, 0.f};

    const int rA = min(r0 + c, N - 1);
    const float* ap = A + (size_t)rA * K + g * 8;

    float av[8];
    *(float4*)&av[0] = *(const float4*)(ap);
    *(float4*)&av[4] = *(const float4*)(ap + 4);

    for (int kg = 0; kg < KG; ++kg) {
        float nv[8];
        if (kg + 1 < KG) {
            *(float4*)&nv[0] = *(const float4*)(ap + (kg + 1) * 32);
            *(float4*)&nv[4] = *(const float4*)(ap + (kg + 1) * 32 + 4);
        }
        bf16x8 ah, al;
#pragma unroll
        for (int j = 0; j < 8; ++j) {
            unsigned short h = f2bf(av[j]);
            ah[j] = (short)h;
            al[j] = (short)f2bf(av[j] - bf2f(h));
        }
#pragma unroll
        for (int f = 0; f < NF; ++f) {
            size_t boff = ((size_t)(f * KG + kg) * 64 + lane) * 8;
            bf16x8 bh = *(const bf16x8*)(whi + boff);
            bf16x8 bl = *(const bf16x8*)(wlo + boff);
            acc[f] = __builtin_amdgcn_mfma_f32_16x16x32_bf16(al, bh, acc[f], 0, 0, 0);
            acc[f] = __builtin_amdgcn_mfma_f32_16x16x32_bf16(ah, bl, acc[f], 0, 0, 0);
            acc[f] = __builtin_amdgcn_mfma_f32_16x16x32_bf16(ah, bh, acc[f], 0, 0, 0);
        }
#pragma unroll
        for (int j = 0; j < 8; ++j) av[j] = nv[j];
    }

    // C/D: col = lane&15, row(within 16) = g*4 + reg
#pragma unroll
    for (int reg = 0; reg < 4; reg++) {
        int row = r0 + g * 4 + reg;
        if (row < N) {
            float sc = dinv[row];
#pragma unroll
            for (int f = 0; f < NF; f++)
                Cout[(size_t)row * M + f * 16 + c] = f2bf(acc[f][reg] * sc);
        }
    }
}

// ------- layers 2-4 GEMM: C_bf16 = dinv ⊙ (A_bf16[N,K] @ W[K,M]); 2-term, 16 rows/wave -------

template <int K, int M>
__global__ __launch_bounds__(256) void k_gemm_bf(const unsigned short* __restrict__ A,
                                                 const unsigned short* __restrict__ whi,
                                                 const unsigned short* __restrict__ wlo,
                                                 const float* __restrict__ dinv,
                                                 unsigned short* __restrict__ Cout, int N) {
    constexpr int NF = M / 16;
    constexpr int KG = K / 32;
    const int wave = threadIdx.x >> 6;
    const int lane = threadIdx.x & 63;
    const int c = lane & 15, g = lane >> 4;
    const int r0 = blockIdx.x * 64 + wave * 16;

    f32x4 acc[NF];
#pragma unroll
    for (int f = 0; f < NF; f++) acc[f] = (f32x4){0.f, 0.f, 0.f, 0.f};

    const int rA = min(r0 + c, N - 1);
    const unsigned short* ap = A + (size_t)rA * K + g * 8;

#pragma unroll
    for (int kg = 0; kg < KG; ++kg) {
        bf16x8 af = *(const bf16x8*)(ap + kg * 32);
#pragma unroll
        for (int f = 0; f < NF; ++f) {
            size_t boff = ((size_t)(f * KG + kg) * 64 + lane) * 8;
            bf16x8 bh = *(const bf16x8*)(whi + boff);
            bf16x8 bl = *(const bf16x8*)(wlo + boff);
            acc[f] = __builtin_amdgcn_mfma_f32_16x16x32_bf16(af, bl, acc[f], 0, 0, 0);
            acc[f] = __builtin_amdgcn_mfma_f32_16x16x32_bf16(af, bh, acc[f], 0, 0, 0);
        }
    }

#pragma unroll
    for (int reg = 0; reg < 4; reg++) {
        int row = r0 + g * 4 + reg;
        if (row < N) {
            float sc = dinv[row];
#pragma unroll
            for (int f = 0; f < NF; f++)
                Cout[(size_t)row * M + f * 16 + c] = f2bf(acc[f][reg] * sc);
        }
    }
}

// ---- aggregate (M=128, bf16 rows in AND out): out = relu(dn*(g[n]+Σ g[src]) + b) ----
// g rows pre-scaled by dinv; one wave/node; lane holds features {2l, 2l+1} packed in a uint

__global__ __launch_bounds__(256) void k_aggbf(const unsigned* __restrict__ g,
                                               const int* __restrict__ offs,
                                               const int* __restrict__ ssrc,
                                               const float* __restrict__ dinv,
                                               const float* __restrict__ bias,
                                               unsigned* __restrict__ out, int N) {
    int wid = (int)(((size_t)blockIdx.x * blockDim.x + threadIdx.x) >> 6);
    int lane = threadIdx.x & 63;
    if (wid >= N) return;
    const int n = wid;
    const float dn = dinv[n];
    unsigned u = g[(size_t)n * 64 + lane];          // self (already dinv-scaled)
    float ax = bflo(u), ay = bfhi(u);
    const int e0 = offs[n], e1 = offs[n + 1];
    int j = e0;
    for (; j + 4 <= e1; j += 4) {
        int s0 = ssrc[j], s1 = ssrc[j + 1], s2 = ssrc[j + 2], s3 = ssrc[j + 3];
        unsigned u0 = g[(size_t)s0 * 64 + lane];
        unsigned u1 = g[(size_t)s1 * 64 + lane];
        unsigned u2 = g[(size_t)s2 * 64 + lane];
        unsigned u3 = g[(size_t)s3 * 64 + lane];
        ax += bflo(u0); ay += bfhi(u0);
        ax += bflo(u1); ay += bfhi(u1);
        ax += bflo(u2); ay += bfhi(u2);
        ax += bflo(u3); ay += bfhi(u3);
    }
    for (; j < e1; ++j) {
        unsigned uu = g[(size_t)ssrc[j] * 64 + lane];
        ax += bflo(uu); ay += bfhi(uu);
    }
    float2 b = ((const float2*)bias)[lane];
    float ox = fmaxf(fmaf(dn, ax, b.x), 0.f);
    float oy = fmaxf(fmaf(dn, ay, b.y), 0.f);
    out[(size_t)n * 64 + lane] = ((unsigned)f2bf(oy) << 16) | (unsigned)f2bf(ox);
}

// ---------------- final aggregate (M=64, bf16 rows) + log_softmax, fp32 out ----------------

__global__ __launch_bounds__(256) void k_agg64f(const unsigned short* __restrict__ g,
                                                const int* __restrict__ offs,
                                                const int* __restrict__ ssrc,
                                                const float* __restrict__ dinv,
                                                const float* __restrict__ bias,
                                                float* __restrict__ out, int N) {
    int wid = (int)(((size_t)blockIdx.x * blockDim.x + threadIdx.x) >> 6);
    int lane = threadIdx.x & 63;
    if (wid >= N) return;
    const int n = wid;
    const float dn = dinv[n];
    float acc = bf2f(g[(size_t)n * 64 + lane]);
    const int e0 = offs[n], e1 = offs[n + 1];
    int j = e0;
    for (; j + 4 <= e1; j += 4) {
        int s0 = ssrc[j], s1 = ssrc[j + 1], s2 = ssrc[j + 2], s3 = ssrc[j + 3];
        float v0 = bf2f(g[(size_t)s0 * 64 + lane]);
        float v1 = bf2f(g[(size_t)s1 * 64 + lane]);
        float v2 = bf2f(g[(size_t)s2 * 64 + lane]);
        float v3 = bf2f(g[(size_t)s3 * 64 + lane]);
        acc += v0 + v1 + v2 + v3;
    }
    for (; j < e1; ++j) acc += bf2f(g[(size_t)ssrc[j] * 64 + lane]);
    float v = fmaxf(fmaf(dn, acc, bias[lane]), 0.f);
    float m = v;
#pragma unroll
    for (int d = 1; d < 64; d <<= 1) m = fmaxf(m, __shfl_xor(m, d));
    float ex = expf(v - m);
    float ssum = ex;
#pragma unroll
    for (int d = 1; d < 64; d <<= 1) ssum += __shfl_xor(ssum, d);
    out[(size_t)n * 64 + lane] = v - m - logf(ssum);
}

// ---------------- launcher ----------------

extern "C" void kernel_launch(void* const* d_in, const int* in_sizes, int n_in,
                              void* d_out, int out_size, void* d_ws, size_t ws_size,
                              hipStream_t stream) {
    const float* x  = (const float*)d_in[0];
    const int*   ei = (const int*)d_in[1];
    const float* W1 = (const float*)d_in[2];
    const float* b1 = (const float*)d_in[3];
    const float* W2 = (const float*)d_in[4];
    const float* b2 = (const float*)d_in[5];
    const float* W3 = (const float*)d_in[6];
    const float* b3 = (const float*)d_in[7];
    const float* W4 = (const float*)d_in[8];
    const float* b4 = (const float*)d_in[9];

    const int N = in_sizes[0] / IN_DIM;   // 100000
    const int E = in_sizes[1] / 2;        // 1600000
    const int* src = ei;
    const int* dst = ei + E;

    char* p = (char*)d_ws;
    unsigned short* hbf = (unsigned short*)p; p += (size_t)N * HID * 2;   // gemm out (bf16)
    unsigned short* abf = (unsigned short*)p; p += (size_t)N * HID * 2;   // agg out (bf16)
    unsigned short* h4  = (unsigned short*)p; p += (size_t)N * OUT_DIM * 2; // gemm4 out (bf16)
    float* dinv = (float*)p;          p += (size_t)N * sizeof(float);
    int* counts = (int*)p;            p += (size_t)N * sizeof(int);
    int* offs   = (int*)p;            p += (size_t)(N + 1) * sizeof(int);
    int* cursor = (int*)p;            p += (size_t)N * sizeof(int);
    int* bsums  = (int*)p;            p += 256 * sizeof(int);
    int* ssrc   = (int*)p;            p += (size_t)E * sizeof(int);
    unsigned short* w1h = (unsigned short*)p; p += (size_t)IN_DIM * HID * 2;
    unsigned short* w1l = (unsigned short*)p; p += (size_t)IN_DIM * HID * 2;
    unsigned short* w2h = (unsigned short*)p; p += (size_t)HID * HID * 2;
    unsigned short* w2l = (unsigned short*)p; p += (size_t)HID * HID * 2;
    unsigned short* w3h = (unsigned short*)p; p += (size_t)HID * HID * 2;
    unsigned short* w3l = (unsigned short*)p; p += (size_t)HID * HID * 2;
    unsigned short* w4h = (unsigned short*)p; p += (size_t)HID * OUT_DIM * 2;
    unsigned short* w4l = (unsigned short*)p; p += (size_t)HID * OUT_DIM * 2;

    hipMemsetAsync(counts, 0, (size_t)N * sizeof(int), stream);

    const int eb = (E + 255) / 256;
    const int nb = (N + 1023) / 1024;
    k_hist<<<eb, 256, 0, stream>>>(dst, E, counts);
    k_scan1<<<nb, 1024, 0, stream>>>(counts, N, offs, bsums);
    k_scan2<<<1, 256, 0, stream>>>(bsums, nb);
    k_scan3<<<nb, 1024, 0, stream>>>(offs, bsums, N, E, cursor);
    k_dinv<<<(N + 255) / 256, 256, 0, stream>>>(counts, N, dinv);
    k_fill<<<eb, 256, 0, stream>>>(src, dst, E, cursor, ssrc);

    k_splitW<<<(IN_DIM * HID + 255) / 256, 256, 0, stream>>>(W1, IN_DIM, HID, w1h, w1l);
    k_splitW<<<(HID * HID + 255) / 256, 256, 0, stream>>>(W2, HID, HID, w2h, w2l);
    k_splitW<<<(HID * HID + 255) / 256, 256, 0, stream>>>(W3, HID, HID, w3h, w3l);
    k_splitW<<<(HID * OUT_DIM + 255) / 256, 256, 0, stream>>>(W4, HID, OUT_DIM, w4h, w4l);

    const int gb = (N + 63) / 64;     // 64 rows / block (16 per wave)
    const int ab = (N + 3) / 4;
    k_gemm1<IN_DIM, HID><<<gb, 256, 0, stream>>>(x, w1h, w1l, dinv, hbf, N);
    k_aggbf<<<ab, 256, 0, stream>>>((const unsigned*)hbf, offs, ssrc, dinv, b1, (unsigned*)abf, N);
    k_gemm_bf<HID, HID><<<gb, 256, 0, stream>>>(abf, w2h, w2l, dinv, hbf, N);
    k_aggbf<<<ab, 256, 0, stream>>>((const unsigned*)hbf, offs, ssrc, dinv, b2, (unsigned*)abf, N);
    k_gemm_bf<HID, HID><<<gb, 256, 0, stream>>>(abf, w3h, w3l, dinv, hbf, N);
    k_aggbf<<<ab, 256, 0, stream>>>((const unsigned*)hbf, offs, ssrc, dinv, b3, (unsigned*)abf, N);
    k_gemm_bf<HID, OUT_DIM><<<gb, 256, 0, stream>>>(abf, w4h, w4l, dinv, h4, N);
    k_agg64f<<<ab, 256, 0, stream>>>(h4, offs, ssrc, dinv, b4, (float*)d_out, N);
}

// Round 5
// 612.594 us; speedup vs baseline: 1.1734x; 1.1734x over previous
//
#include <hip/hip_runtime.h>
#include <cstdint>
#include <cstddef>

static constexpr int IN_DIM = 512;
static constexpr int HID = 128;
static constexpr int OUT_DIM = 64;

typedef __attribute__((ext_vector_type(8))) short bf16x8;
typedef __attribute__((ext_vector_type(4))) float f32x4;

__device__ inline unsigned short f2bf(float x) {
    unsigned u = __float_as_uint(x);
    unsigned r = (u + 0x7FFFu + ((u >> 16) & 1u)) >> 16;   // RNE
    return (unsigned short)r;
}
__device__ inline float bf2f(unsigned short b) { return __uint_as_float(((unsigned)b) << 16); }
__device__ inline float bflo(unsigned u) { return __uint_as_float(u << 16); }
__device__ inline float bfhi(unsigned u) { return __uint_as_float(u & 0xFFFF0000u); }

// global->LDS direct load, 16B per lane. dest = wave-uniform base (+lane*16 by HW),
// src = per-lane global address. AS(3) via low-32 of generic LDS address (CK idiom).
__device__ inline void gload_lds16(const void* g, void* l) {
    __builtin_amdgcn_global_load_lds(
        (const __attribute__((address_space(1))) unsigned int*)g,
        (__attribute__((address_space(3))) unsigned int*)(unsigned long long)(uintptr_t)l,
        16, 0, 0);
}

// ---------------- CSR construction (counting sort by dst, rebuilt every call) ----------------

__global__ void k_hist(const int* __restrict__ dst, int E, int* __restrict__ counts) {
    int e = blockIdx.x * blockDim.x + threadIdx.x;
    if (e < E) atomicAdd(&counts[dst[e]], 1);
}

__global__ void k_scan1(const int* __restrict__ counts, int N, int* __restrict__ offs,
                        int* __restrict__ bsums) {
    __shared__ int sm[1024];
    int i = blockIdx.x * 1024 + threadIdx.x;
    int v = (i < N) ? counts[i] : 0;
    sm[threadIdx.x] = v;
    __syncthreads();
    for (int d = 1; d < 1024; d <<= 1) {
        int t = (threadIdx.x >= d) ? sm[threadIdx.x - d] : 0;
        __syncthreads();
        sm[threadIdx.x] += t;
        __syncthreads();
    }
    if (i < N) offs[i] = sm[threadIdx.x] - v;
    if (threadIdx.x == 1023) bsums[blockIdx.x] = sm[1023];
}

__global__ void k_scan2(int* __restrict__ bsums, int nb) {
    __shared__ int sm[256];
    int x = threadIdx.x;
    int v = (x < nb) ? bsums[x] : 0;
    sm[x] = v;
    __syncthreads();
    for (int d = 1; d < 256; d <<= 1) {
        int t = (x >= d) ? sm[x - d] : 0;
        __syncthreads();
        sm[x] += t;
        __syncthreads();
    }
    if (x < nb) bsums[x] = sm[x] - v;
}

__global__ void k_scan3(int* __restrict__ offs, const int* __restrict__ bsums, int N, int E,
                        int* __restrict__ cursor) {
    int i = blockIdx.x * 1024 + threadIdx.x;
    if (i < N) {
        int o = offs[i] + bsums[blockIdx.x];
        offs[i] = o;
        cursor[i] = o;
    }
    if (blockIdx.x == 0 && threadIdx.x == 0) offs[N] = E;
}

__global__ void k_dinv(const int* __restrict__ counts, int N, float* __restrict__ dinv) {
    int i = blockIdx.x * blockDim.x + threadIdx.x;
    if (i < N) dinv[i] = rsqrtf((float)(counts[i] + 1));
}

__global__ void k_fill(const int* __restrict__ src, const int* __restrict__ dst, int E,
                       int* __restrict__ cursor, int* __restrict__ ssrc) {
    int e = blockIdx.x * blockDim.x + threadIdx.x;
    if (e < E) {
        int p = atomicAdd(&cursor[dst[e]], 1);
        ssrc[p] = src[e];
    }
}

// ---------------- W pack: per-kg contiguous MFMA B-fragment blocks (hi/lo interleaved) -------
// slot = (((kg*NF + f)*2 + h)*64 + l)*8 + j ; col = f*16 + (l&15), k = kg*32 + (l>>4)*8 + j

__global__ void k_packW(const float* __restrict__ W, int K, int M,
                        unsigned short* __restrict__ wpk) {
    int idx = blockIdx.x * 256 + threadIdx.x;
    int total = K * M * 2;
    if (idx >= total) return;
    int j = idx & 7;
    int l = (idx >> 3) & 63;
    int h = (idx >> 9) & 1;
    int rest = idx >> 10;
    int NF = M >> 4;
    int f = rest % NF;
    int kg = rest / NF;
    int k = kg * 32 + (l >> 4) * 8 + j;
    int col = f * 16 + (l & 15);
    float v = W[(size_t)k * M + col];
    unsigned short hi = f2bf(v);
    wpk[idx] = h ? f2bf(v - bf2f(hi)) : hi;
}

// ------- layer-1 GEMM: C_bf16 = dinv ⊙ (A_f32[N,K] @ W[K,M]); 3-term split, LDS-staged B -----
// block = 256 thr = 4 waves; 128 rows/block, 32 rows/wave (2 row-fragments)

template <int K, int M>
__global__ __launch_bounds__(256) void k_gemm1(const float* __restrict__ A,
                                               const unsigned short* __restrict__ wpk,
                                               const float* __restrict__ dinv,
                                               unsigned short* __restrict__ Cout, int N) {
    constexpr int NF = M / 16;                 // 8
    constexpr int KG = K / 32;                 // 16
    constexpr int KGB = NF * 2 * 1024;         // bytes per kg block (16384)
    constexpr int NISS = KGB / 4096;           // global_load_lds issues per wave (4)
    __shared__ unsigned char smem[2][KGB];

    const int wave = threadIdx.x >> 6;
    const int lane = threadIdx.x & 63;
    const int c = lane & 15, g = lane >> 4;
    const int r0 = blockIdx.x * 128 + wave * 32;

    f32x4 acc[2][NF];
#pragma unroll
    for (int m = 0; m < 2; m++)
#pragma unroll
        for (int f = 0; f < NF; f++) acc[m][f] = (f32x4){0.f, 0.f, 0.f, 0.f};

    const int rA0 = min(r0 + c, N - 1);
    const int rA1 = min(r0 + 16 + c, N - 1);
    const float* ap0 = A + (size_t)rA0 * K + g * 8;
    const float* ap1 = A + (size_t)rA1 * K + g * 8;

#define STAGE1(kg_, buf_)                                                              \
    {                                                                                  \
        _Pragma("unroll") for (int i = 0; i < NISS; ++i) {                             \
            const unsigned short* gsrc =                                               \
                wpk + (((size_t)(kg_)*KGB + (size_t)i * 4096 + (size_t)wave * 1024) >> 1) + \
                (size_t)lane * 8;                                                      \
            gload_lds16(gsrc, &smem[buf_][i * 4096 + wave * 1024]);                    \
        }                                                                              \
    }

    STAGE1(0, 0);
    float av0[8], av1[8];
    *(float4*)&av0[0] = *(const float4*)(ap0);
    *(float4*)&av0[4] = *(const float4*)(ap0 + 4);
    *(float4*)&av1[0] = *(const float4*)(ap1);
    *(float4*)&av1[4] = *(const float4*)(ap1 + 4);
    __syncthreads();

    int buf = 0;
    for (int kg = 0; kg < KG; ++kg) {
        if (kg + 1 < KG) STAGE1(kg + 1, buf ^ 1);
        float nv0[8], nv1[8];
        if (kg + 1 < KG) {
            *(float4*)&nv0[0] = *(const float4*)(ap0 + (kg + 1) * 32);
            *(float4*)&nv0[4] = *(const float4*)(ap0 + (kg + 1) * 32 + 4);
            *(float4*)&nv1[0] = *(const float4*)(ap1 + (kg + 1) * 32);
            *(float4*)&nv1[4] = *(const float4*)(ap1 + (kg + 1) * 32 + 4);
        }
        bf16x8 ah0, al0, ah1, al1;
#pragma unroll
        for (int j = 0; j < 8; ++j) {
            unsigned short h0 = f2bf(av0[j]);
            unsigned short h1 = f2bf(av1[j]);
            ah0[j] = (short)h0;
            ah1[j] = (short)h1;
            al0[j] = (short)f2bf(av0[j] - bf2f(h0));
            al1[j] = (short)f2bf(av1[j] - bf2f(h1));
        }
#pragma unroll
        for (int f = 0; f < NF; ++f) {
            bf16x8 bh = *(const bf16x8*)&smem[buf][(f * 2 + 0) * 1024 + lane * 16];
            bf16x8 bl = *(const bf16x8*)&smem[buf][(f * 2 + 1) * 1024 + lane * 16];
            acc[0][f] = __builtin_amdgcn_mfma_f32_16x16x32_bf16(al0, bh, acc[0][f], 0, 0, 0);
            acc[0][f] = __builtin_amdgcn_mfma_f32_16x16x32_bf16(ah0, bl, acc[0][f], 0, 0, 0);
            acc[0][f] = __builtin_amdgcn_mfma_f32_16x16x32_bf16(ah0, bh, acc[0][f], 0, 0, 0);
            acc[1][f] = __builtin_amdgcn_mfma_f32_16x16x32_bf16(al1, bh, acc[1][f], 0, 0, 0);
            acc[1][f] = __builtin_amdgcn_mfma_f32_16x16x32_bf16(ah1, bl, acc[1][f], 0, 0, 0);
            acc[1][f] = __builtin_amdgcn_mfma_f32_16x16x32_bf16(ah1, bh, acc[1][f], 0, 0, 0);
        }
        if (kg + 1 < KG) {
#pragma unroll
            for (int j = 0; j < 8; ++j) { av0[j] = nv0[j]; av1[j] = nv1[j]; }
        }
        __syncthreads();   // drains vmcnt(0): next buf staged; all waves done reading buf
        buf ^= 1;
    }
#undef STAGE1

    // C/D: col = lane&15, row = m*16 + (lane>>4)*4 + reg
#pragma unroll
    for (int m = 0; m < 2; m++) {
#pragma unroll
        for (int reg = 0; reg < 4; reg++) {
            int row = r0 + m * 16 + g * 4 + reg;
            if (row < N) {
                float sc = dinv[row];
#pragma unroll
                for (int f = 0; f < NF; f++)
                    Cout[(size_t)row * M + f * 16 + c] = f2bf(acc[m][f][reg] * sc);
            }
        }
    }
}

// ------- layers 2-4 GEMM: C_bf16 = dinv ⊙ (A_bf16[N,K] @ W[K,M]); 2-term, LDS-staged B ------
// A row (K=128) fully preloaded into registers; 32 rows/wave

template <int K, int M>
__global__ __launch_bounds__(256) void k_gemm_bf(const unsigned short* __restrict__ A,
                                                 const unsigned short* __restrict__ wpk,
                                                 const float* __restrict__ dinv,
                                                 unsigned short* __restrict__ Cout, int N) {
    constexpr int NF = M / 16;
    constexpr int KG = K / 32;                 // 4
    constexpr int KGB = NF * 2 * 1024;
    constexpr int NISS = KGB / 4096;
    __shared__ unsigned char smem[2][KGB];

    const int wave = threadIdx.x >> 6;
    const int lane = threadIdx.x & 63;
    const int c = lane & 15, g = lane >> 4;
    const int r0 = blockIdx.x * 128 + wave * 32;

    f32x4 acc[2][NF];
#pragma unroll
    for (int m = 0; m < 2; m++)
#pragma unroll
        for (int f = 0; f < NF; f++) acc[m][f] = (f32x4){0.f, 0.f, 0.f, 0.f};

    const int rA0 = min(r0 + c, N - 1);
    const int rA1 = min(r0 + 16 + c, N - 1);
    const unsigned short* ap0 = A + (size_t)rA0 * K + g * 8;
    const unsigned short* ap1 = A + (size_t)rA1 * K + g * 8;

#define STAGE2(kg_, buf_)                                                              \
    {                                                                                  \
        _Pragma("unroll") for (int i = 0; i < NISS; ++i) {                             \
            const unsigned short* gsrc =                                               \
                wpk + (((size_t)(kg_)*KGB + (size_t)i * 4096 + (size_t)wave * 1024) >> 1) + \
                (size_t)lane * 8;                                                      \
            gload_lds16(gsrc, &smem[buf_][i * 4096 + wave * 1024]);                    \
        }                                                                              \
    }

    STAGE2(0, 0);
    bf16x8 af0[KG], af1[KG];
#pragma unroll
    for (int kg = 0; kg < KG; ++kg) {
        af0[kg] = *(const bf16x8*)(ap0 + kg * 32);
        af1[kg] = *(const bf16x8*)(ap1 + kg * 32);
    }
    __syncthreads();

    int buf = 0;
#pragma unroll
    for (int kg = 0; kg < KG; ++kg) {
        if (kg + 1 < KG) STAGE2(kg + 1, buf ^ 1);
#pragma unroll
        for (int f = 0; f < NF; ++f) {
            bf16x8 bh = *(const bf16x8*)&smem[buf][(f * 2 + 0) * 1024 + lane * 16];
            bf16x8 bl = *(const bf16x8*)&smem[buf][(f * 2 + 1) * 1024 + lane * 16];
            acc[0][f] = __builtin_amdgcn_mfma_f32_16x16x32_bf16(af0[kg], bl, acc[0][f], 0, 0, 0);
            acc[0][f] = __builtin_amdgcn_mfma_f32_16x16x32_bf16(af0[kg], bh, acc[0][f], 0, 0, 0);
            acc[1][f] = __builtin_amdgcn_mfma_f32_16x16x32_bf16(af1[kg], bl, acc[1][f], 0, 0, 0);
            acc[1][f] = __builtin_amdgcn_mfma_f32_16x16x32_bf16(af1[kg], bh, acc[1][f], 0, 0, 0);
        }
        __syncthreads();
        buf ^= 1;
    }
#undef STAGE2

#pragma unroll
    for (int m = 0; m < 2; m++) {
#pragma unroll
        for (int reg = 0; reg < 4; reg++) {
            int row = r0 + m * 16 + g * 4 + reg;
            if (row < N) {
                float sc = dinv[row];
#pragma unroll
                for (int f = 0; f < NF; f++)
                    Cout[(size_t)row * M + f * 16 + c] = f2bf(acc[m][f][reg] * sc);
            }
        }
    }
}

// ---- aggregate (M=128, bf16 rows in AND out): out = relu(dn*(g[n]+Σ g[src]) + b) ----

__global__ __launch_bounds__(256) void k_aggbf(const unsigned* __restrict__ g,
                                               const int* __restrict__ offs,
                                               const int* __restrict__ ssrc,
                                               const float* __restrict__ dinv,
                                               const float* __restrict__ bias,
                                               unsigned* __restrict__ out, int N) {
    int wid = (int)(((size_t)blockIdx.x * blockDim.x + threadIdx.x) >> 6);
    int lane = threadIdx.x & 63;
    if (wid >= N) return;
    const int n = wid;
    const float dn = dinv[n];
    unsigned u = g[(size_t)n * 64 + lane];
    float ax = bflo(u), ay = bfhi(u);
    const int e0 = offs[n], e1 = offs[n + 1];
    int j = e0;
    for (; j + 4 <= e1; j += 4) {
        int s0 = ssrc[j], s1 = ssrc[j + 1], s2 = ssrc[j + 2], s3 = ssrc[j + 3];
        unsigned u0 = g[(size_t)s0 * 64 + lane];
        unsigned u1 = g[(size_t)s1 * 64 + lane];
        unsigned u2 = g[(size_t)s2 * 64 + lane];
        unsigned u3 = g[(size_t)s3 * 64 + lane];
        ax += bflo(u0); ay += bfhi(u0);
        ax += bflo(u1); ay += bfhi(u1);
        ax += bflo(u2); ay += bfhi(u2);
        ax += bflo(u3); ay += bfhi(u3);
    }
    for (; j < e1; ++j) {
        unsigned uu = g[(size_t)ssrc[j] * 64 + lane];
        ax += bflo(uu); ay += bfhi(uu);
    }
    float2 b = ((const float2*)bias)[lane];
    float ox = fmaxf(fmaf(dn, ax, b.x), 0.f);
    float oy = fmaxf(fmaf(dn, ay, b.y), 0.f);
    out[(size_t)n * 64 + lane] = ((unsigned)f2bf(oy) << 16) | (unsigned)f2bf(ox);
}

// ---------------- final aggregate (M=64, bf16 rows) + log_softmax, fp32 out ----------------

__global__ __launch_bounds__(256) void k_agg64f(const unsigned short* __restrict__ g,
                                                const int* __restrict__ offs,
                                                const int* __restrict__ ssrc,
                                                const float* __restrict__ dinv,
                                                const float* __restrict__ bias,
                                                float* __restrict__ out, int N) {
    int wid = (int)(((size_t)blockIdx.x * blockDim.x + threadIdx.x) >> 6);
    int lane = threadIdx.x & 63;
    if (wid >= N) return;
    const int n = wid;
    const float dn = dinv[n];
    float acc = bf2f(g[(size_t)n * 64 + lane]);
    const int e0 = offs[n], e1 = offs[n + 1];
    int j = e0;
    for (; j + 4 <= e1; j += 4) {
        int s0 = ssrc[j], s1 = ssrc[j + 1], s2 = ssrc[j + 2], s3 = ssrc[j + 3];
        float v0 = bf2f(g[(size_t)s0 * 64 + lane]);
        float v1 = bf2f(g[(size_t)s1 * 64 + lane]);
        float v2 = bf2f(g[(size_t)s2 * 64 + lane]);
        float v3 = bf2f(g[(size_t)s3 * 64 + lane]);
        acc += v0 + v1 + v2 + v3;
    }
    for (; j < e1; ++j) acc += bf2f(g[(size_t)ssrc[j] * 64 + lane]);
    float v = fmaxf(fmaf(dn, acc, bias[lane]), 0.f);
    float m = v;
#pragma unroll
    for (int d = 1; d < 64; d <<= 1) m = fmaxf(m, __shfl_xor(m, d));
    float ex = expf(v - m);
    float ssum = ex;
#pragma unroll
    for (int d = 1; d < 64; d <<= 1) ssum += __shfl_xor(ssum, d);
    out[(size_t)n * 64 + lane] = v - m - logf(ssum);
}

// ---------------- launcher ----------------

extern "C" void kernel_launch(void* const* d_in, const int* in_sizes, int n_in,
                              void* d_out, int out_size, void* d_ws, size_t ws_size,
                              hipStream_t stream) {
    const float* x  = (const float*)d_in[0];
    const int*   ei = (const int*)d_in[1];
    const float* W1 = (const float*)d_in[2];
    const float* b1 = (const float*)d_in[3];
    const float* W2 = (const float*)d_in[4];
    const float* b2 = (const float*)d_in[5];
    const float* W3 = (const float*)d_in[6];
    const float* b3 = (const float*)d_in[7];
    const float* W4 = (const float*)d_in[8];
    const float* b4 = (const float*)d_in[9];

    const int N = in_sizes[0] / IN_DIM;   // 100000
    const int E = in_sizes[1] / 2;        // 1600000
    const int* src = ei;
    const int* dst = ei + E;

    char* p = (char*)d_ws;
    unsigned short* hbf = (unsigned short*)p; p += (size_t)N * HID * 2;     // gemm out (bf16)
    unsigned short* abf = (unsigned short*)p; p += (size_t)N * HID * 2;     // agg out (bf16)
    unsigned short* h4  = (unsigned short*)p; p += (size_t)N * OUT_DIM * 2; // gemm4 out (bf16)
    float* dinv = (float*)p;          p += (size_t)N * sizeof(float);
    int* counts = (int*)p;            p += (size_t)N * sizeof(int);
    int* offs   = (int*)p;            p += (size_t)(N + 1) * sizeof(int);
    int* cursor = (int*)p;            p += (size_t)N * sizeof(int);
    int* bsums  = (int*)p;            p += 256 * sizeof(int);
    int* ssrc   = (int*)p;            p += (size_t)E * sizeof(int);
    unsigned short* w1p = (unsigned short*)p; p += (size_t)IN_DIM * HID * 2 * 2;
    unsigned short* w2p = (unsigned short*)p; p += (size_t)HID * HID * 2 * 2;
    unsigned short* w3p = (unsigned short*)p; p += (size_t)HID * HID * 2 * 2;
    unsigned short* w4p = (unsigned short*)p; p += (size_t)HID * OUT_DIM * 2 * 2;

    hipMemsetAsync(counts, 0, (size_t)N * sizeof(int), stream);

    const int eb = (E + 255) / 256;
    const int nb = (N + 1023) / 1024;
    k_hist<<<eb, 256, 0, stream>>>(dst, E, counts);
    k_scan1<<<nb, 1024, 0, stream>>>(counts, N, offs, bsums);
    k_scan2<<<1, 256, 0, stream>>>(bsums, nb);
    k_scan3<<<nb, 1024, 0, stream>>>(offs, bsums, N, E, cursor);
    k_dinv<<<(N + 255) / 256, 256, 0, stream>>>(counts, N, dinv);
    k_fill<<<eb, 256, 0, stream>>>(src, dst, E, cursor, ssrc);

    k_packW<<<(IN_DIM * HID * 2 + 255) / 256, 256, 0, stream>>>(W1, IN_DIM, HID, w1p);
    k_packW<<<(HID * HID * 2 + 255) / 256, 256, 0, stream>>>(W2, HID, HID, w2p);
    k_packW<<<(HID * HID * 2 + 255) / 256, 256, 0, stream>>>(W3, HID, HID, w3p);
    k_packW<<<(HID * OUT_DIM * 2 + 255) / 256, 256, 0, stream>>>(W4, HID, OUT_DIM, w4p);

    const int gb = (N + 127) / 128;    // 128 rows / block (32 per wave)
    const int ab = (N + 3) / 4;
    k_gemm1<IN_DIM, HID><<<gb, 256, 0, stream>>>(x, w1p, dinv, hbf, N);
    k_aggbf<<<ab, 256, 0, stream>>>((const unsigned*)hbf, offs, ssrc, dinv, b1, (unsigned*)abf, N);
    k_gemm_bf<HID, HID><<<gb, 256, 0, stream>>>(abf, w2p, dinv, hbf, N);
    k_aggbf<<<ab, 256, 0, stream>>>((const unsigned*)hbf, offs, ssrc, dinv, b2, (unsigned*)abf, N);
    k_gemm_bf<HID, HID><<<gb, 256, 0, stream>>>(abf, w3p, dinv, hbf, N);
    k_aggbf<<<ab, 256, 0, stream>>>((const unsigned*)hbf, offs, ssrc, dinv, b3, (unsigned*)abf, N);
    k_gemm_bf<HID, OUT_DIM><<<gb, 256, 0, stream>>>(abf, w4p, dinv, h4, N);
    k_agg64f<<<ab, 256, 0, stream>>>(h4, offs, ssrc, dinv, b4, (float*)d_out, N);
}